// Round 4
// baseline (179.812 us; speedup 1.0000x reference)
//
#include <hip/hip_runtime.h>

// Problem constants (from reference).
#define N_GENOMES 30000
#define N_GENES   240000
#define N_SAMPLES 128
#define N_SEQS    80000
#define CAP       32   // max genes per seq bucket (Poisson mean = 3; P(overflow) ~ 3e-17)

// ---------------------------------------------------------------------------
// Kernel 1: bucket-scatter genes by sequence id (fat {genome,pos} records),
// and build a locality-preserving seq processing order: the gene whose
// atomicAdd returns slot 0 is its seq's first toucher; wave-aggregated
// ballot compaction appends that seq to order[]. Since genome_idx is sorted
// over genes, consecutive genes share genome rows -> seqs adjacent in
// order[] reuse the same A/B rows at nearly the same time in accum.
// ---------------------------------------------------------------------------
__global__ __launch_bounds__(256) void scatter_kernel(
    const int*   __restrict__ seq_idx,
    const int*   __restrict__ genome_idx,
    const float* __restrict__ pos,
    int*         __restrict__ cnt,        // N_SEQS, zeroed
    int*         __restrict__ order_cnt,  // 1, zeroed
    int*         __restrict__ order,      // N_SEQS
    int2*        __restrict__ bucket)     // N_SEQS * CAP
{
    int  gene  = blockIdx.x * blockDim.x + threadIdx.x;
    bool valid = gene < N_GENES;          // no early return: all lanes reach ballot
    int  s = 0, slot = -1;

    if (valid) {
        s = seq_idx[gene];
        int2 rec;
        rec.x = genome_idx[gene];          // coalesced (gene-ordered)
        rec.y = __float_as_int(pos[gene]); // coalesced
        slot  = atomicAdd(&cnt[s], 1);
        if (slot < CAP) bucket[s * CAP + slot] = rec;
    }

    // Wave-aggregated append of first-touch seqs (one atomic per wave).
    bool flag = valid && (slot == 0);
    unsigned long long mask = __ballot(flag);
    if (mask != 0ull) {
        int lane   = threadIdx.x & 63;
        int leader = __ffsll((unsigned long long)mask) - 1;
        int rank   = __popcll(mask & ((1ull << lane) - 1ull));
        int base   = 0;
        if (lane == leader) base = atomicAdd(order_cnt, __popcll(mask));
        base = __shfl(base, leader, 64);
        if (flag) order[base + rank] = s;
    }
}

// ---------------------------------------------------------------------------
// Kernel 2: owner-computes segment sum, chunk-of-4 pipeline, processing seqs
// in order[] (first-gene order) so concurrent waves hit overlapping genome
// rows -> L2 captures the ~8x row reuse instead of L3/HBM.
// Wave-slots >= *order_cnt are seqs with zero genes: d_out is pre-zeroed.
// ---------------------------------------------------------------------------
__global__ __launch_bounds__(256) void accum_kernel(
    const float* __restrict__ A,
    const float* __restrict__ B,
    const int*   __restrict__ cnt,
    const int*   __restrict__ order_cnt,
    const int*   __restrict__ order,
    const int2*  __restrict__ bucket,
    float*       __restrict__ out)
{
    int idx  = blockIdx.x * blockDim.x + threadIdx.x;
    int w    = idx >> 5;                  // wave-slot: 32 lanes = 32 quads of one seq
    int quad = idx & 31;
    if (w >= N_SEQS) return;

    int nlist = *order_cnt;               // scalar, L2-hot
    if (w >= nlist) return;               // zero-gene seqs stay zero (pre-memset)
    int seq = order[w];

    int n = cnt[seq];
    if (n > CAP) n = CAP;

    const int2*   bk = bucket + seq * CAP;
    const float4* A4 = reinterpret_cast<const float4*>(A);
    const float4* B4 = reinterpret_cast<const float4*>(B);

    float4 acc = make_float4(0.f, 0.f, 0.f, 0.f);

    for (int i0 = 0; i0 < n; i0 += 4) {
        int2   r[4];
        int    g[4];
        float  p[4];
        bool   live[4];
        float4 a[4], b[4];

        #pragma unroll
        for (int j = 0; j < 4; ++j) {
            live[j] = (i0 + j) < n;
            r[j] = bk[i0 + j];               // always within CAP slots
        }
        #pragma unroll
        for (int j = 0; j < 4; ++j) {
            g[j] = live[j] ? r[j].x : 0;     // sentinel row 0 for dead slots
            p[j] = __int_as_float(r[j].y);
        }
        #pragma unroll
        for (int j = 0; j < 4; ++j) {        // 8 independent row loads in flight
            a[j] = A4[g[j] * 32 + quad];
            b[j] = B4[g[j] * 32 + quad];
        }
        #pragma unroll
        for (int j = 0; j < 4; ++j) {
            float4 e;
            e.x = __expf(a[j].x + 1.0f - p[j] * b[j].x);
            e.y = __expf(a[j].y + 1.0f - p[j] * b[j].y);
            e.z = __expf(a[j].z + 1.0f - p[j] * b[j].z);
            e.w = __expf(a[j].w + 1.0f - p[j] * b[j].w);
            if (live[j]) {
                acc.x += e.x; acc.y += e.y; acc.z += e.z; acc.w += e.w;
            }
        }
    }

    reinterpret_cast<float4*>(out)[seq * 32 + quad] = acc;
}

extern "C" void kernel_launch(void* const* d_in, const int* in_sizes, int n_in,
                              void* d_out, int out_size, void* d_ws, size_t ws_size,
                              hipStream_t stream) {
    const float* A    = (const float*)d_in[0];
    const float* B    = (const float*)d_in[1];
    const float* pos  = (const float*)d_in[2];
    const int*   gidx = (const int*)d_in[3];
    const int*   sidx = (const int*)d_in[4];
    float*       out  = (float*)d_out;

    // Workspace layout (ints):
    //   [0, N_SEQS)            cnt
    //   [N_SEQS]               order_cnt
    //   [N_SEQS+1, 2*N_SEQS+1) order
    //   [2*N_SEQS+2, ...)      bucket (int2, 8B-aligned: (2*N_SEQS+2)*4 % 8 == 0)
    int*  wsi       = (int*)d_ws;
    int*  cnt       = wsi;
    int*  order_cnt = wsi + N_SEQS;
    int*  order     = wsi + N_SEQS + 1;
    int2* bucket    = (int2*)(wsi + 2 * N_SEQS + 2);

    // d_ws/d_out are re-poisoned 0xAA before every launch.
    hipMemsetAsync(cnt, 0, (N_SEQS + 1) * sizeof(int), stream);          // cnt + order_cnt
    hipMemsetAsync(out, 0, (size_t)out_size * sizeof(float), stream);    // zero-gene seqs

    scatter_kernel<<<(N_GENES + 255) / 256, 256, 0, stream>>>(
        sidx, gidx, pos, cnt, order_cnt, order, bucket);

    const int total = N_SEQS * 32;   // 2,560,000 threads
    accum_kernel<<<(total + 255) / 256, 256, 0, stream>>>(
        A, B, cnt, order_cnt, order, bucket, out);
}

// Round 5
// 125.742 us; speedup vs baseline: 1.4300x; 1.4300x over previous
//
#include <hip/hip_runtime.h>
#include <hip/hip_fp16.h>

// Problem constants (from reference).
#define N_GENOMES 30000
#define N_GENES   240000
#define N_SAMPLES 128
#define N_SEQS    80000
#define CAP       32   // max genes per seq (Poisson mean 3; P(overflow) ~ 3e-17)

#define SCATTER_BLOCKS  ((N_GENES + 255) / 256)        // 938
#define COMPRESS_BLOCKS ((N_GENOMES * 32 + 255) / 256) // 3750 (exact: 960000/256)

// ---------------------------------------------------------------------------
// Fused prep kernel.
// Blocks [0, SCATTER_BLOCKS): bucket-scatter genes by seq id with PACKED 4B
//   records: genome (15 bits) | pos quantized to 17 bits. pos*131072 is exact
//   in fp32 (power-of-2 scale), so truncation error <= 2^-17.
// Blocks [SCATTER_BLOCKS, ...): compress A/B to fp16 interleaved per quad:
//   {a0+1,a1+1,a2+1,a3+1, b0,b1,b2,b3} = 16B per (genome, quad) -> accum does
//   ONE 16B load per gene instead of two 16B loads.
// Scatter blocks first: their atomic latency overlaps the compress streaming.
// ---------------------------------------------------------------------------
__global__ __launch_bounds__(256) void prep_kernel(
    const float* __restrict__ A,
    const float* __restrict__ B,
    const float* __restrict__ pos,
    const int*   __restrict__ genome_idx,
    const int*   __restrict__ seq_idx,
    int*          __restrict__ cnt,     // N_SEQS, zeroed
    unsigned int* __restrict__ bucket,  // N_SEQS * CAP packed records
    float4*       __restrict__ AB16)    // N_GENOMES*32 x 16B interleaved fp16
{
    int b = blockIdx.x;
    if (b < SCATTER_BLOCKS) {
        int gene = b * 256 + threadIdx.x;
        if (gene >= N_GENES) return;
        int   s = seq_idx[gene];
        int   g = genome_idx[gene];
        float p = pos[gene];
        unsigned int q   = (unsigned int)(p * 131072.0f);   // exact mul, trunc -> [0,131071]
        unsigned int rec = (unsigned int)g | (q << 15);
        int slot = atomicAdd(&cnt[s], 1);
        if (slot < CAP) bucket[s * CAP + slot] = rec;
    } else {
        int idx = (b - SCATTER_BLOCKS) * 256 + threadIdx.x; // genome*32 + quad, < 960000
        const float4 a  = reinterpret_cast<const float4*>(A)[idx];
        const float4 bb = reinterpret_cast<const float4*>(B)[idx];
        __half2 h[4];
        h[0] = __floats2half2_rn(a.x + 1.0f, a.y + 1.0f);   // fold the +1 here
        h[1] = __floats2half2_rn(a.z + 1.0f, a.w + 1.0f);
        h[2] = __floats2half2_rn(bb.x, bb.y);
        h[3] = __floats2half2_rn(bb.z, bb.w);
        AB16[idx] = *reinterpret_cast<float4*>(h);          // one 16B store
    }
}

// ---------------------------------------------------------------------------
// Accum kernel (round-3 structure, compressed payload).
// One thread per (seq, quad): 32 lanes = one seq, half-wave reads one full
// 512B interleaved row per gene. Chunk-of-4 pipeline: 4 record loads ->
// 4 independent 16B row loads in flight -> decode fp16, exp, predicated acc.
// Every out element is written (n==0 -> zeros), so no out memset needed.
// ---------------------------------------------------------------------------
__global__ __launch_bounds__(256) void accum_kernel(
    const float4*       __restrict__ AB16,
    const int*          __restrict__ cnt,
    const unsigned int* __restrict__ bucket,
    float*              __restrict__ out)
{
    int idx  = blockIdx.x * blockDim.x + threadIdx.x;
    int seq  = idx >> 5;
    int quad = idx & 31;
    if (seq >= N_SEQS) return;

    int n = cnt[seq];
    if (n > CAP) n = CAP;

    const unsigned int* bk = bucket + seq * CAP;
    float4 acc = make_float4(0.f, 0.f, 0.f, 0.f);

    for (int i0 = 0; i0 < n; i0 += 4) {
        unsigned int r[4];
        float        p[4];
        bool         live[4];
        float4       raw[4];

        #pragma unroll
        for (int j = 0; j < 4; ++j) {
            live[j] = (i0 + j) < n;
            r[j] = bk[i0 + j];                    // within CAP slots always
        }
        #pragma unroll
        for (int j = 0; j < 4; ++j) {
            if (!live[j]) r[j] = 0;               // sentinel: row 0 (L1-hot), p=0
            p[j] = (float)(r[j] >> 15) * (1.0f / 131072.0f);
        }
        #pragma unroll
        for (int j = 0; j < 4; ++j) {             // 4 independent 16B loads in flight
            int g = (int)(r[j] & 0x7fffu);
            raw[j] = AB16[g * 32 + quad];
        }
        #pragma unroll
        for (int j = 0; j < 4; ++j) {
            const __half2* hp = reinterpret_cast<const __half2*>(&raw[j]);
            float2 a01 = __half22float2(hp[0]);
            float2 a23 = __half22float2(hp[1]);
            float2 b01 = __half22float2(hp[2]);
            float2 b23 = __half22float2(hp[3]);
            float4 e;
            e.x = __expf(a01.x - p[j] * b01.x);   // a already has +1 folded in
            e.y = __expf(a01.y - p[j] * b01.y);
            e.z = __expf(a23.x - p[j] * b23.x);
            e.w = __expf(a23.y - p[j] * b23.y);
            if (live[j]) {
                acc.x += e.x; acc.y += e.y; acc.z += e.z; acc.w += e.w;
            }
        }
    }

    reinterpret_cast<float4*>(out)[seq * 32 + quad] = acc;
}

extern "C" void kernel_launch(void* const* d_in, const int* in_sizes, int n_in,
                              void* d_out, int out_size, void* d_ws, size_t ws_size,
                              hipStream_t stream) {
    const float* A    = (const float*)d_in[0];
    const float* B    = (const float*)d_in[1];
    const float* pos  = (const float*)d_in[2];
    const int*   gidx = (const int*)d_in[3];
    const int*   sidx = (const int*)d_in[4];
    float*       out  = (float*)d_out;

    // Workspace layout (256 MiB available, ~26 MB used):
    //   [0, 15360000)             AB16: 960000 float4 (16B-aligned at base)
    //   [15360000, 15680000)      cnt: N_SEQS ints
    //   [15680000, 25920000)      bucket: N_SEQS*CAP uints
    char*         ws     = (char*)d_ws;
    float4*       AB16   = (float4*)ws;
    int*          cnt    = (int*)(ws + (size_t)N_GENOMES * 32 * 16);
    unsigned int* bucket = (unsigned int*)(cnt + N_SEQS);

    // d_ws is re-poisoned 0xAA before every launch; zero the counters only.
    hipMemsetAsync(cnt, 0, N_SEQS * sizeof(int), stream);

    prep_kernel<<<SCATTER_BLOCKS + COMPRESS_BLOCKS, 256, 0, stream>>>(
        A, B, pos, gidx, sidx, cnt, bucket, AB16);

    const int total = N_SEQS * 32;   // 2,560,000 threads
    accum_kernel<<<(total + 255) / 256, 256, 0, stream>>>(
        AB16, cnt, bucket, out);
}